// Round 2
// baseline (986.768 us; speedup 1.0000x reference)
//
#include <hip/hip_runtime.h>
#include <float.h>

#define NV   20000
#define NP   35
#define NPTS 700000

// ws float offsets
#define S1SUM 0
#define S1SQ  16
#define S2SUM 32
#define S2SQ  96
#define S3SUM 160
#define S3SQ  288
#define SC1   416
#define SH1   432
#define SC2   448
#define SH2   512
#define SC3   576
#define SH3   704
#define M3MAX 1024
#define M3MIN (1024 + NV*128)

__global__ __launch_bounds__(256) void k_stats1(const float* __restrict__ x,
    const float* __restrict__ W1, const float* __restrict__ b1, float* __restrict__ ws)
{
  __shared__ float sW1[112], sb1[16];
  __shared__ float red[4][32];
  int t = threadIdx.x;
  if (t < 112) sW1[t] = W1[t];
  if (t < 16)  sb1[t] = b1[t];
  __syncthreads();
  float s[16], ss[16];
  #pragma unroll
  for (int u=0;u<16;++u){ s[u]=0.f; ss[u]=0.f; }
  int stride = gridDim.x * blockDim.x;
  for (int p = blockIdx.x*blockDim.x + t; p < NPTS; p += stride) {
    float xv[7];
    #pragma unroll
    for (int c=0;c<7;++c) xv[c] = x[p*7+c];
    #pragma unroll
    for (int u=0;u<16;++u) {
      float h = sb1[u];
      #pragma unroll
      for (int c=0;c<7;++c) h = fmaf(xv[c], sW1[c*16+u], h);
      s[u] += h; ss[u] = fmaf(h,h,ss[u]);
    }
  }
  #pragma unroll
  for (int u=0;u<16;++u) {
    #pragma unroll
    for (int off=32; off>0; off>>=1) {
      s[u]  += __shfl_xor(s[u],  off);
      ss[u] += __shfl_xor(ss[u], off);
    }
  }
  int wid = t>>6, lane = t&63;
  if (lane == 0) {
    #pragma unroll
    for (int u=0;u<16;++u){ red[wid][u]=s[u]; red[wid][16+u]=ss[u]; }
  }
  __syncthreads();
  if (t < 32) {
    float a = red[0][t]+red[1][t]+red[2][t]+red[3][t];
    atomicAdd(&ws[S1SUM + t], a);
  }
}

__global__ void k_finalize(const float* __restrict__ sum, const float* __restrict__ sq,
    const float* __restrict__ g, const float* __restrict__ be,
    float* __restrict__ scale, float* __restrict__ shift, int C)
{
  int u = threadIdx.x;
  if (u < C) {
    const float invN = 1.f/(float)NPTS;
    float mean = sum[u]*invN;
    float var  = sq[u]*invN - mean*mean;
    float sc = g[u] * rsqrtf(var + 1e-5f);
    scale[u] = sc;
    shift[u] = fmaf(-mean, sc, be[u]);
  }
}

// STAGE==2: compute through layer-2 preact, accumulate BN2 stats.
// STAGE==3: recompute layers 1-2, layer-3 preact, BN3 stats + per-voxel max/min.
template<int STAGE>
__global__ __launch_bounds__(256) void k_pass(
    const float* __restrict__ x,
    const float* __restrict__ W1, const float* __restrict__ b1,
    const float* __restrict__ W2, const float* __restrict__ b2,
    const float* __restrict__ Wd, const float* __restrict__ bd,
    float* __restrict__ ws)
{
  constexpr int NW = 4;
  __shared__ float sW1[112], sb1v[16], ssc1[16], ssh1[16];
  __shared__ __align__(16) float h1n_lds[NW][NP][20];   // padded rows, 16B-aligned
  __shared__ float keep_lds[NW][NP + 1];
  __shared__ __align__(16) float h2n_lds[STAGE==3 ? NW : 1][STAGE==3 ? NP : 1][64];
  __shared__ __align__(16) float agg2_lds[STAGE==3 ? NW : 1][64];
  __shared__ __align__(16) float sWd[STAGE==3 ? 128*128 : 4];

  int t = threadIdx.x;
  if (t < 112) sW1[t] = W1[t];
  if (t < 16) { sb1v[t]=b1[t]; ssc1[t]=ws[SC1+t]; ssh1[t]=ws[SH1+t]; }
  if constexpr (STAGE==3) {
    for (int i = t*4; i < 128*128; i += 256*4)
      *reinterpret_cast<float4*>(&sWd[i]) = *reinterpret_cast<const float4*>(&Wd[i]);
  }
  __syncthreads();

  int lane = t & 63, w = t >> 6;
  float W2r[32];
  #pragma unroll
  for (int c=0;c<32;++c) W2r[c] = W2[c*64 + lane];
  float b2r = b2[lane];
  float sc2r=0.f, sh2r=0.f, bdr0=0.f, bdr1=0.f;
  if constexpr (STAGE==3) {
    sc2r = ws[SC2+lane]; sh2r = ws[SH2+lane];
    bdr0 = bd[lane]; bdr1 = bd[64+lane];
  }
  float s2=0.f, ss2=0.f;
  float s3a=0.f, ss3a=0.f, s3b=0.f, ss3b=0.f;
  float* m3x = ws + M3MAX;
  float* m3n = ws + M3MIN;

  int wave = (blockIdx.x * blockDim.x + t) >> 6;
  int nw = (gridDim.x * blockDim.x) >> 6;
  for (int v = wave; v < NV; v += nw) {
    // ---- Phase A: lane = point ----
    int p = lane;
    float xv[7];
    float kp = 0.f;
    if (p < NP) {
      float sum = 0.f;
      #pragma unroll
      for (int c=0;c<7;++c){ xv[c] = x[(v*NP + p)*7 + c]; sum += xv[c]; }
      kp = (sum == 0.f) ? 0.f : 1.f;
    } else {
      #pragma unroll
      for (int c=0;c<7;++c) xv[c]=0.f;
    }
    float h1v[16];
    #pragma unroll
    for (int u=0;u<16;++u) h1v[u] = sb1v[u];
    #pragma unroll
    for (int c=0;c<7;++c){
      float xc = xv[c];
      #pragma unroll
      for (int u=0;u<16;++u) h1v[u] = fmaf(xc, sW1[c*16+u], h1v[u]);
    }
    float aggv[16];
    #pragma unroll
    for (int u=0;u<16;++u){
      float hn = fmaxf(0.f, fmaf(h1v[u], ssc1[u], ssh1[u]));
      h1v[u] = hn;
      aggv[u] = (p < NP) ? hn : -FLT_MAX;
    }
    #pragma unroll
    for (int u=0;u<16;++u){
      #pragma unroll
      for (int off=32; off>0; off>>=1)
        aggv[u] = fmaxf(aggv[u], __shfl_xor(aggv[u], off));
    }
    if (p < NP) {
      #pragma unroll
      for (int c=0;c<16;c+=4)
        *reinterpret_cast<float4*>(&h1n_lds[w][p][c]) =
            make_float4(h1v[c],h1v[c+1],h1v[c+2],h1v[c+3]);
      keep_lds[w][p] = kp;
    }
    // ---- Phase B: lane = channel u in [0,64) ----
    float t1 = 0.f;
    #pragma unroll
    for (int c=0;c<16;++c) t1 = fmaf(aggv[c], W2r[16+c], t1);
    float agg2u = -FLT_MAX;
    #pragma unroll
    for (int p2=0;p2<NP;++p2){
      float kpp = keep_lds[w][p2];
      float d = t1;
      #pragma unroll
      for (int c=0;c<16;c+=4){
        float4 a = *reinterpret_cast<const float4*>(&h1n_lds[w][p2][c]);
        d = fmaf(a.x, W2r[c],   d);
        d = fmaf(a.y, W2r[c+1], d);
        d = fmaf(a.z, W2r[c+2], d);
        d = fmaf(a.w, W2r[c+3], d);
      }
      float h2p = fmaf(kpp, d, b2r);
      if constexpr (STAGE==2) {
        s2 += h2p; ss2 = fmaf(h2p, h2p, ss2);
      } else {
        float h2nv = fmaxf(0.f, fmaf(h2p, sc2r, sh2r));
        agg2u = fmaxf(agg2u, h2nv);
        h2n_lds[w][p2][lane] = h2nv;
      }
    }
    // ---- Phase C (stage 3): lane owns output channels {lane, lane+64} ----
    if constexpr (STAGE==3) {
      agg2_lds[w][lane] = agg2u;
      float t3a=0.f, t3b=0.f;
      #pragma unroll
      for (int c=0;c<64;++c){
        float a = agg2_lds[w][c];
        t3a = fmaf(a, sWd[(64+c)*128 + lane],      t3a);
        t3b = fmaf(a, sWd[(64+c)*128 + 64 + lane], t3b);
      }
      float acc0[NP], acc1[NP];
      #pragma unroll
      for (int p2=0;p2<NP;++p2){ acc0[p2]=0.f; acc1[p2]=0.f; }
      for (int cb=0; cb<64; cb+=4){
        float w00=sWd[(cb+0)*128+lane],    w01=sWd[(cb+1)*128+lane],
              w02=sWd[(cb+2)*128+lane],    w03=sWd[(cb+3)*128+lane];
        float w10=sWd[(cb+0)*128+64+lane], w11=sWd[(cb+1)*128+64+lane],
              w12=sWd[(cb+2)*128+64+lane], w13=sWd[(cb+3)*128+64+lane];
        #pragma unroll
        for (int p2=0;p2<NP;++p2){
          float4 a = *reinterpret_cast<const float4*>(&h2n_lds[w][p2][cb]);
          acc0[p2] = fmaf(a.x,w00, fmaf(a.y,w01, fmaf(a.z,w02, fmaf(a.w,w03, acc0[p2]))));
          acc1[p2] = fmaf(a.x,w10, fmaf(a.y,w11, fmaf(a.z,w12, fmaf(a.w,w13, acc1[p2]))));
        }
      }
      float mx0=-FLT_MAX, mx1=-FLT_MAX, mn0=FLT_MAX, mn1=FLT_MAX;
      #pragma unroll
      for (int p2=0;p2<NP;++p2){
        float kpp = keep_lds[w][p2];
        float h0 = fmaf(kpp, acc0[p2]+t3a, bdr0);
        float h1 = fmaf(kpp, acc1[p2]+t3b, bdr1);
        s3a += h0; ss3a = fmaf(h0,h0,ss3a);
        s3b += h1; ss3b = fmaf(h1,h1,ss3b);
        mx0=fmaxf(mx0,h0); mn0=fminf(mn0,h0);
        mx1=fmaxf(mx1,h1); mn1=fminf(mn1,h1);
      }
      m3x[v*128+lane]    = mx0;  m3x[v*128+64+lane] = mx1;
      m3n[v*128+lane]    = mn0;  m3n[v*128+64+lane] = mn1;
    }
  }
  if constexpr (STAGE==2) {
    atomicAdd(&ws[S2SUM+lane], s2);
    atomicAdd(&ws[S2SQ +lane], ss2);
  } else {
    atomicAdd(&ws[S3SUM+lane],    s3a);
    atomicAdd(&ws[S3SUM+64+lane], s3b);
    atomicAdd(&ws[S3SQ+lane],     ss3a);
    atomicAdd(&ws[S3SQ+64+lane],  ss3b);
  }
}

__global__ __launch_bounds__(256) void k_scatter(const float* __restrict__ ws,
    const int* __restrict__ coord, float* __restrict__ out)
{
  int tid = blockIdx.x*blockDim.x + threadIdx.x;
  if (tid >= NV*128) return;
  int v = tid >> 7, u = tid & 127;
  float sc = ws[SC3+u], sh = ws[SH3+u];
  // BN is monotone per channel: max_p relu(BN(h)) = relu(BN(max_p h)) if sc>=0,
  // else relu(BN(min_p h)). Pick by sign.
  float m = (sc >= 0.f) ? ws[M3MAX+tid] : ws[M3MIN+tid];
  float val = fmaxf(0.f, fmaf(m, sc, sh));
  if (val != 0.f) {
    int z = coord[v*3+0], y = coord[v*3+1], xx = coord[v*3+2];
    atomicAdd(&out[((u*10+z)*200+y)*176+xx], val);
  }
}

extern "C" void kernel_launch(void* const* d_in, const int* in_sizes, int n_in,
                              void* d_out, int out_size, void* d_ws, size_t ws_size,
                              hipStream_t stream)
{
  const float* x   = (const float*)d_in[0];
  const int*   coord = (const int*)d_in[1];
  const float* W1  = (const float*)d_in[2];
  const float* b1  = (const float*)d_in[3];
  const float* g1  = (const float*)d_in[4];
  const float* be1 = (const float*)d_in[5];
  const float* W2  = (const float*)d_in[6];
  const float* b2  = (const float*)d_in[7];
  const float* g2  = (const float*)d_in[8];
  const float* be2 = (const float*)d_in[9];
  const float* Wd  = (const float*)d_in[10];
  const float* bd  = (const float*)d_in[11];
  const float* gd  = (const float*)d_in[12];
  const float* bed = (const float*)d_in[13];
  float* out = (float*)d_out;
  float* ws  = (float*)d_ws;

  hipMemsetAsync(ws, 0, 416*sizeof(float), stream);
  hipMemsetAsync(out, 0, (size_t)out_size*sizeof(float), stream);

  k_stats1<<<640,256,0,stream>>>(x, W1, b1, ws);
  k_finalize<<<1,128,0,stream>>>(ws+S1SUM, ws+S1SQ, g1, be1, ws+SC1, ws+SH1, 16);
  k_pass<2><<<1024,256,0,stream>>>(x, W1,b1,W2,b2,Wd,bd, ws);
  k_finalize<<<1,128,0,stream>>>(ws+S2SUM, ws+S2SQ, g2, be2, ws+SC2, ws+SH2, 64);
  k_pass<3><<<512,256,0,stream>>>(x, W1,b1,W2,b2,Wd,bd, ws);
  k_finalize<<<1,128,0,stream>>>(ws+S3SUM, ws+S3SQ, gd, bed, ws+SC3, ws+SH3, 128);
  k_scatter<<<(NV*128+255)/256,256,0,stream>>>(ws, coord, out);
}